// Round 17
// baseline (574.205 us; speedup 1.0000x reference)
//
#include <hip/hip_runtime.h>
#include <math.h>

#define DIM 64
#define NT 4
#define NR 8
// tmeta layout: [0..3]=tcnt  [4..7]=tbase  [8..11]=tfill  [12]=padded_total

typedef __attribute__((ext_vector_type(8))) short bf16x8;   // 8 bf16 (4 VGPRs)
typedef __attribute__((ext_vector_type(8))) unsigned short u16x8;
typedef __attribute__((ext_vector_type(4))) float f32x4;    // 4 fp32 acc

// ---- bf16 helpers (bit-level; values finite/small) ----
__device__ __forceinline__ unsigned short f2bf(float f) {
    unsigned u = __float_as_uint(f);
    return (unsigned short)((u + 0x7FFF + ((u >> 16) & 1)) >> 16);  // RNE
}
__device__ __forceinline__ float bf2f(unsigned short u) {
    return __uint_as_float((unsigned)u << 16);
}
__device__ __forceinline__ bf16x8 ldb16(const unsigned short* p) {
    return *((const bf16x8*)p);
}

// ---- prep: weight transpose+cast, plus workspace zero-init (fused) ----
// mats: 0..7 = rel_att, 8..15 = rel_msg, 16..19 = k_lin, 20..23 = q_lin, 24..27 = v_lin
__global__ void prep_all(const float* __restrict__ A, const float* __restrict__ Mw,
                         const float* __restrict__ kl, const float* __restrict__ ql,
                         const float* __restrict__ vl,
                         unsigned short* __restrict__ At, unsigned short* __restrict__ Mt,
                         unsigned short* __restrict__ Wkt, unsigned short* __restrict__ Wqt,
                         unsigned short* __restrict__ Wvt,
                         int* __restrict__ cnt8, int* __restrict__ tm, int M2) {
    int i = blockIdx.x * blockDim.x + threadIdx.x;
    if (i < M2) cnt8[i] = 0;
    if (i < 16) tm[i] = 0;
    if (i >= 28 * DIM * DIM) return;
    int mat = i >> 12;
    int idx = i & 4095;
    int n = idx >> 6;
    int k = idx & 63;
    int so = k * DIM + n;
    if (mat < 8)       At [((size_t)mat << 12) + idx]        = f2bf(A [((size_t)mat << 12) + so]);
    else if (mat < 16) Mt [((size_t)(mat - 8) << 12) + idx]  = f2bf(Mw[((size_t)(mat - 8) << 12) + so]);
    else if (mat < 20) Wkt[((size_t)(mat - 16) << 12) + idx] = f2bf(kl[((size_t)(mat - 16) << 12) + so]);
    else if (mat < 24) Wqt[((size_t)(mat - 20) << 12) + idx] = f2bf(ql[((size_t)(mat - 20) << 12) + so]);
    else               Wvt[((size_t)(mat - 24) << 12) + idx] = f2bf(vl[((size_t)(mat - 24) << 12) + so]);
}

// ---- per-wave ballot histogram of node types (+ order=-1 init, fused) ----
__global__ void type_count(const int* __restrict__ ntype, int* __restrict__ tm,
                           int* __restrict__ order, int N, int ocap2) {
    int i = blockIdx.x * blockDim.x + threadIdx.x;
    if (i < ocap2) order[i] = -1;
    int t = (i < N) ? ntype[i] : -1;
    int lane = threadIdx.x & 63;
    #pragma unroll
    for (int tt = 0; tt < NT; tt++) {
        unsigned long long m = __ballot(t == tt);
        int c = __popcll(m);
        if (c && lane == (__ffsll((long long)m) - 1)) atomicAdd(&tm[tt], c);
    }
}

__global__ void type_scan(int* __restrict__ tm) {
    if (threadIdx.x == 0 && blockIdx.x == 0) {
        int b = 0;
        for (int t = 0; t < NT; t++) { tm[4 + t] = b; b += ((tm[t] + 63) >> 6) << 6; }
        tm[12] = b;
    }
}

// ---- scatter to sorted order; also writes pos[] (inverse permutation) ----
__global__ void type_scatter(const int* __restrict__ ntype, int* __restrict__ tm,
                             int* __restrict__ order, int* __restrict__ pos, int N) {
    int i = blockIdx.x * blockDim.x + threadIdx.x;
    int t = (i < N) ? ntype[i] : -1;
    int lane = threadIdx.x & 63;
    #pragma unroll
    for (int tt = 0; tt < NT; tt++) {
        unsigned long long m = __ballot(t == tt);
        int c = __popcll(m);
        if (!c) continue;
        int ldr = __ffsll((long long)m) - 1;
        int base = 0;
        if (lane == ldr) base = atomicAdd(&tm[8 + tt], c);
        base = __shfl(base, ldr, 64);
        if (t == tt) {
            int rank = __popcll(m & ((1ull << lane) - 1ull));
            int p = tm[4 + tt] + base + rank;
            order[p] = i;
            pos[i] = p;
        }
    }
}

// ---- typed K/Q/V projection via MFMA: sorted 64-node tile, LDS-staged
// coalesced stores. q written in SORTED layout; kv natural. ----
__global__ void __launch_bounds__(256)
proj_mfma(const float* __restrict__ h, const int* __restrict__ ntype,
          const int* __restrict__ order, const int* __restrict__ tm,
          const unsigned short* __restrict__ Wkt, const unsigned short* __restrict__ Wqt,
          const unsigned short* __restrict__ Wvt,
          unsigned short* __restrict__ kvbf, unsigned short* __restrict__ qbf, int N) {
    __shared__ __align__(16) unsigned short xs[64][72];
    int t  = threadIdx.x;
    int n0 = blockIdx.x * 64;
    if (n0 >= tm[12]) return;
    int first = order[n0];
    if (first < 0) return;
    int ty = ntype[first];

    // row -> global node (for h gather and kv scatter)
    int grow[2];
    #pragma unroll
    for (int i = 0; i < 2; i++) grow[i] = order[n0 + (t + 256 * i) / 8];

    // stage h tile as bf16 (padding rows = exact zeros)
    #pragma unroll
    for (int i = 0; i < 4; i++) {
        int idx = t + 256 * i;
        int row = idx >> 4, c4 = idx & 15;
        int gn = order[n0 + row];
        float4 xv = make_float4(0.f, 0.f, 0.f, 0.f);
        if (gn >= 0) xv = ((const float4*)(h + (size_t)gn * DIM))[c4];
        ushort4 b = make_ushort4(f2bf(xv.x), f2bf(xv.y), f2bf(xv.z), f2bf(xv.w));
        *((ushort4*)&xs[row][c4 * 4]) = b;
    }
    __syncthreads();

    int wave = t >> 6, lane = t & 63;
    int m = lane & 15, quad = lane >> 4;
    bf16x8 xa0 = *((const bf16x8*)&xs[wave * 16 + m][quad * 8]);
    bf16x8 xa1 = *((const bf16x8*)&xs[wave * 16 + m][32 + quad * 8]);

    const unsigned short* Wt[3] = { Wkt + (size_t)ty * 4096,
                                    Wqt + (size_t)ty * 4096,
                                    Wvt + (size_t)ty * 4096 };
    for (int mm = 0; mm < 3; mm++) {
        const unsigned short* W = Wt[mm];
        f32x4 c0 = {0.f,0.f,0.f,0.f}, c1 = c0, c2 = c0, c3 = c0;
        c0 = __builtin_amdgcn_mfma_f32_16x16x32_bf16(xa0, ldb16(W + (( 0 + m) << 6)      + quad * 8), c0, 0, 0, 0);
        c1 = __builtin_amdgcn_mfma_f32_16x16x32_bf16(xa0, ldb16(W + ((16 + m) << 6)      + quad * 8), c1, 0, 0, 0);
        c2 = __builtin_amdgcn_mfma_f32_16x16x32_bf16(xa0, ldb16(W + ((32 + m) << 6)      + quad * 8), c2, 0, 0, 0);
        c3 = __builtin_amdgcn_mfma_f32_16x16x32_bf16(xa0, ldb16(W + ((48 + m) << 6)      + quad * 8), c3, 0, 0, 0);
        c0 = __builtin_amdgcn_mfma_f32_16x16x32_bf16(xa1, ldb16(W + (( 0 + m) << 6) + 32 + quad * 8), c0, 0, 0, 0);
        c1 = __builtin_amdgcn_mfma_f32_16x16x32_bf16(xa1, ldb16(W + ((16 + m) << 6) + 32 + quad * 8), c1, 0, 0, 0);
        c2 = __builtin_amdgcn_mfma_f32_16x16x32_bf16(xa1, ldb16(W + ((32 + m) << 6) + 32 + quad * 8), c2, 0, 0, 0);
        c3 = __builtin_amdgcn_mfma_f32_16x16x32_bf16(xa1, ldb16(W + ((48 + m) << 6) + 32 + quad * 8), c3, 0, 0, 0);

        // D (row=quad*4+reg, col=m+16*nb) -> LDS stage (xs reused)
        __syncthreads();
        #pragma unroll
        for (int reg = 0; reg < 4; reg++) {
            unsigned short* qr = &xs[wave * 16 + quad * 4 + reg][m];
            qr[ 0] = f2bf(c0[reg]); qr[16] = f2bf(c1[reg]);
            qr[32] = f2bf(c2[reg]); qr[48] = f2bf(c3[reg]);
        }
        __syncthreads();
        // coalesced 16B stores
        #pragma unroll
        for (int i = 0; i < 2; i++) {
            int idx = t + 256 * i;
            int row = idx >> 3, c8 = idx & 7;
            u16x8 v = *((const u16x8*)&xs[row][c8 * 8]);
            if (mm == 1) {
                *((u16x8*)(qbf + ((size_t)(n0 + row) << 6) + c8 * 8)) = v;
            } else {
                int gn = grow[i];
                if (gn >= 0) {
                    unsigned short* dp = (mm == 0)
                        ? kvbf + ((size_t)gn << 7) + c8 * 8
                        : kvbf + ((size_t)gn << 7) + 64 + c8 * 8;
                    *((u16x8*)dp) = v;
                }
            }
        }
    }
}

// ------- CSR build over (pos(dst)*8 + etype) buckets: SORTED-position keys.
// hist8 records each edge's within-bucket rank -> atomic-free scatter. -------
__global__ void hist8(const int* __restrict__ dst, const int* __restrict__ et,
                      const int* __restrict__ pos,
                      int* __restrict__ cnt, int* __restrict__ rank, int E) {
    int e = blockIdx.x * blockDim.x + threadIdx.x;
    if (e < E) rank[e] = atomicAdd(&cnt[pos[dst[e]] * NR + et[e]], 1);
}

// shuffle-based block scan: 3 barriers instead of 20
__global__ void scan1(const int* __restrict__ cnt, int* __restrict__ off,
                      int* __restrict__ bsum, int M) {
    __shared__ int wsum[16];
    int tid = threadIdx.x;
    int lane = tid & 63, wid = tid >> 6;
    int i = blockIdx.x * 1024 + tid;
    int x0 = (i < M) ? cnt[i] : 0;
    int x = x0;
    #pragma unroll
    for (int s = 1; s < 64; s <<= 1) {
        int y = __shfl_up(x, s, 64);
        if (lane >= s) x += y;
    }
    if (lane == 63) wsum[wid] = x;
    __syncthreads();
    if (tid < 16) {
        int w = wsum[tid];
        #pragma unroll
        for (int s = 1; s < 16; s <<= 1) {
            int y = __shfl_up(w, s, 16);
            if (tid >= s) w += y;
        }
        wsum[tid] = w;   // inclusive wave-sum scan
    }
    __syncthreads();
    int add = (wid > 0) ? wsum[wid - 1] : 0;
    if (i < M) off[i] = add + x - x0;            // exclusive
    if (tid == 1023) bsum[blockIdx.x] = wsum[15]; // block total
}

__global__ void scan2(int* __restrict__ bsum, int nb) {
    __shared__ int wsum[16];
    __shared__ int carry;
    int tid = threadIdx.x;
    int lane = tid & 63, wid = tid >> 6;
    if (tid == 0) carry = 0;
    __syncthreads();
    for (int base = 0; base < nb; base += 1024) {
        int i = base + tid;
        int x0 = (i < nb) ? bsum[i] : 0;
        int x = x0;
        #pragma unroll
        for (int s = 1; s < 64; s <<= 1) {
            int y = __shfl_up(x, s, 64);
            if (lane >= s) x += y;
        }
        if (lane == 63) wsum[wid] = x;
        __syncthreads();
        if (tid < 16) {
            int w = wsum[tid];
            #pragma unroll
            for (int s = 1; s < 16; s <<= 1) {
                int y = __shfl_up(w, s, 16);
                if (tid >= s) w += y;
            }
            wsum[tid] = w;
        }
        __syncthreads();
        int add = carry + ((wid > 0) ? wsum[wid - 1] : 0);
        if (i < nb) bsum[i] = add + x - x0;   // exclusive
        __syncthreads();
        if (tid == 0) carry += wsum[15];
        __syncthreads();
    }
}

__global__ void scan3(int* __restrict__ off, const int* __restrict__ bsum, int M, int E) {
    int i = blockIdx.x * 1024 + threadIdx.x;
    if (i < M) off[i] += bsum[blockIdx.x];
    if (i == 0) off[M] = E;
}

__global__ void scatter8(const int* __restrict__ src, const int* __restrict__ dst,
                         const int* __restrict__ et, const int* __restrict__ pos,
                         const int* __restrict__ off,
                         const int* __restrict__ rank, int* __restrict__ se, int E) {
    int e = blockIdx.x * blockDim.x + threadIdx.x;
    if (e >= E) return;
    int key = pos[dst[e]] * NR + et[e];
    se[off[key] + rank[e]] = src[e];
}

// =====================================================================
// Fused edge phase + output GEMM over SORTED tiles (one type per tile).
// CSR keyed by sorted POSITION -> bucket offsets load COALESCED (v12,
// proven). Carried one-round-lookahead FIRST PAIR (v14/v16, proven):
// round r+1's bucket bounds and se[i0], se[i0+1] are loaded during
// round r. NEW (single delta): ROLLING in-loop se prefetch — se[i+2],
// se[i+3] issue at the top of each walk iteration so they complete
// under the current pair's kv gather + dot/exp, removing the ~400cy
// se hop from every subsequent iteration of long buckets (the wave's
// round time is gated by its max-length bucket).
// Epilogue: W2 = sigmoid(skip)*a_lin in LDS; U/D via LDS-aliased f32
// tile; out rows scattered directly.
// =====================================================================
__global__ void __launch_bounds__(256)
fused_edge(const unsigned short* __restrict__ qbf,      // SORTED layout
           const unsigned short* __restrict__ kvbf,     // natural layout
           const unsigned short* __restrict__ At,
           const unsigned short* __restrict__ Mt,
           const int* __restrict__ se, const int* __restrict__ off8,
           const float* __restrict__ rel_pri,
           const int* __restrict__ ntype, const int* __restrict__ order,
           const int* __restrict__ tm,
           const float* __restrict__ Wa, const float* __restrict__ skip,
           float* __restrict__ out, int N) {
    __shared__ __align__(16) unsigned short smem[2][4][16][72]; // qwb | pl (18432B)
    __shared__ __align__(16) float W2[64][64];                  // 16KB
    unsigned short (*qwb)[16][72] = smem[0];
    unsigned short (*pl)[16][72]  = smem[1];
    const int t    = threadIdx.x;
    const int wave = t >> 6;
    const int lane = t & 63;
    const int m    = lane & 15;      // MFMA col
    const int quad = lane >> 4;      // MFMA quad
    const int sg   = lane >> 2;      // walk: node owner (0..15)
    const int ll   = lane & 3;       // walk: dim-16 owner
    const int n0   = blockIdx.x * 64 + wave * 16;   // sorted position base
    const int tot  = tm[12];
    const bool blkvalid = (blockIdx.x * 64) < tot;

    // ---- stage W2 = sigmoid(skip[ty]) * Wa[ty] (block-uniform type) ----
    if (blkvalid) {
        const int ty = ntype[order[blockIdx.x * 64]];
        const float sgs = 1.f / (1.f + expf(-skip[ty]));
        const float4* wg = (const float4*)(Wa + (size_t)ty * DIM * DIM);
        float4* wl = (float4*)&W2[0][0];
        #pragma unroll
        for (int i = 0; i < 4; i++) {
            float4 w = wg[t + 256 * i];
            w.x *= sgs; w.y *= sgs; w.z *= sgs; w.w *= sgs;
            wl[t + 256 * i] = w;
        }
    }
    __syncthreads();
    if (!blkvalid) return;

    // ---- coalesced bucket offsets: 129 values for the wave's 16 positions ----
    const int ob  = n0 * NR;
    const int ov0 = off8[ob + lane];
    const int ov1 = off8[ob + 64 + lane];
    const int ov2 = off8[ob + 128];      // wave-uniform; defined up to off8[M2]=E

    // ---- round-0 bounds + first-pair prefetch ----
    int i0c, i1c, sAc, sBc;
    {
        const int g = sg * NR, g1 = g + 1;
        const int a0_ = __shfl(ov0, g & 63, 64);
        const int b0_ = __shfl(ov1, g & 63, 64);
        i0c = (g < 64) ? a0_ : b0_;
        const int a1_ = __shfl(ov0, g1 & 63, 64);
        const int b1_ = __shfl(ov1, g1 & 63, 64);
        i1c = (g1 < 64) ? a1_ : ((g1 < 128) ? b1_ : ov2);
        sAc = (i0c < i1c)     ? se[i0c]     : 0;
        sBc = (i0c + 1 < i1c) ? se[i0c + 1] : sAc;
    }

    // Q A-frags from sorted qbf (padding rows are zeros)
    const unsigned short* qp = qbf + ((size_t)(n0 + m) << 6) + quad * 8;
    const bf16x8 qa0 = *((const bf16x8*)qp);
    const bf16x8 qa1 = *((const bf16x8*)(qp + 32));

    f32x4 u0 = {0.f,0.f,0.f,0.f}, u1 = u0, u2 = u0, u3 = u0;  // U accumulator
    float ddsum = 0.f;   // node sg's denominator (replicated over 4 lanes)

    for (int r = 0; r < NR; r++) {
        // ---- qW tile via MFMA ----
        const unsigned short* Ar = At + ((size_t)r << 12);
        f32x4 c0 = {0.f,0.f,0.f,0.f}, c1 = c0, c2 = c0, c3 = c0;
        c0 = __builtin_amdgcn_mfma_f32_16x16x32_bf16(qa0, ldb16(Ar + (( 0 + m) << 6)      + quad * 8), c0, 0, 0, 0);
        c1 = __builtin_amdgcn_mfma_f32_16x16x32_bf16(qa0, ldb16(Ar + ((16 + m) << 6)      + quad * 8), c1, 0, 0, 0);
        c2 = __builtin_amdgcn_mfma_f32_16x16x32_bf16(qa0, ldb16(Ar + ((32 + m) << 6)      + quad * 8), c2, 0, 0, 0);
        c3 = __builtin_amdgcn_mfma_f32_16x16x32_bf16(qa0, ldb16(Ar + ((48 + m) << 6)      + quad * 8), c3, 0, 0, 0);
        c0 = __builtin_amdgcn_mfma_f32_16x16x32_bf16(qa1, ldb16(Ar + (( 0 + m) << 6) + 32 + quad * 8), c0, 0, 0, 0);
        c1 = __builtin_amdgcn_mfma_f32_16x16x32_bf16(qa1, ldb16(Ar + ((16 + m) << 6) + 32 + quad * 8), c1, 0, 0, 0);
        c2 = __builtin_amdgcn_mfma_f32_16x16x32_bf16(qa1, ldb16(Ar + ((32 + m) << 6) + 32 + quad * 8), c2, 0, 0, 0);
        c3 = __builtin_amdgcn_mfma_f32_16x16x32_bf16(qa1, ldb16(Ar + ((48 + m) << 6) + 32 + quad * 8), c3, 0, 0, 0);

        #pragma unroll
        for (int reg = 0; reg < 4; reg++) {
            unsigned short* qr = &qwb[wave][quad * 4 + reg][m];
            qr[ 0] = f2bf(c0[reg]); qr[16] = f2bf(c1[reg]);
            qr[32] = f2bf(c2[reg]); qr[48] = f2bf(c3[reg]);
        }
        asm volatile("s_waitcnt lgkmcnt(0)" ::: "memory");

        // ---- current-round bounds/first-pair from carried registers ----
        const int i0  = i0c;
        const int i1  = i1c;
        const int sA1 = sAc;
        const int sB1 = sBc;
        // ---- prefetch NEXT round's bounds + first pair (hidden under walk+MFMA) ----
        if (r < 7) {
            const int g = sg * NR + r + 1, g1 = g + 1;
            const int a0_ = __shfl(ov0, g & 63, 64);
            const int b0_ = __shfl(ov1, g & 63, 64);
            i0c = (g < 64) ? a0_ : b0_;
            const int a1_ = __shfl(ov0, g1 & 63, 64);
            const int b1_ = __shfl(ov1, g1 & 63, 64);
            i1c = (g1 < 64) ? a1_ : ((g1 < 128) ? b1_ : ov2);
            sAc = (i0c < i1c)     ? se[i0c]     : 0;
            sBc = (i0c + 1 < i1c) ? se[i0c + 1] : sAc;
        }

        const float pri = rel_pri[r] * 0.125f;
        float P[16];
        #pragma unroll
        for (int x = 0; x < 16; x++) P[x] = 0.f;
        float dd = 0.f;

        if (i0 < i1) {
            const u16x8 tq0 = *((const u16x8*)&qwb[wave][sg][ll * 16]);
            const u16x8 tq1 = *((const u16x8*)&qwb[wave][sg][ll * 16 + 8]);
            float tq[16];
            #pragma unroll
            for (int x = 0; x < 8; x++) { tq[x] = bf2f(tq0[x]); tq[8 + x] = bf2f(tq1[x]); }

            int i  = i0;
            int sA = sA1;
            int sB = sB1;
            while (true) {
                const bool hB = (i + 1 < i1);
                // rolling prefetch of the NEXT pair's se (completes under the
                // current pair's kv gather + dot/exp)
                int nA = 0, nB = 0;
                if (i + 2 < i1) {
                    nA = se[i + 2];
                    nB = (i + 3 < i1) ? se[i + 3] : nA;
                }
                const unsigned short* pA = kvbf + ((size_t)sA << 7) + ll * 16;
                const unsigned short* pB = kvbf + ((size_t)sB << 7) + ll * 16;
                const u16x8 kA0 = *((const u16x8*)pA);
                const u16x8 kA1 = *((const u16x8*)(pA + 8));
                const u16x8 vA0 = *((const u16x8*)(pA + 64));
                const u16x8 vA1 = *((const u16x8*)(pA + 72));
                const u16x8 kB0 = *((const u16x8*)pB);
                const u16x8 kB1 = *((const u16x8*)(pB + 8));
                const u16x8 vB0 = *((const u16x8*)(pB + 64));
                const u16x8 vB1 = *((const u16x8*)(pB + 72));
                float sa = 0.f, sb = 0.f;
                #pragma unroll
                for (int x = 0; x < 8; x++) {
                    sa = fmaf(bf2f(kA0[x]), tq[x],     sa);
                    sa = fmaf(bf2f(kA1[x]), tq[8 + x], sa);
                    sb = fmaf(bf2f(kB0[x]), tq[x],     sb);
                    sb = fmaf(bf2f(kB1[x]), tq[8 + x], sb);
                }
                sa += __shfl_xor(sa, 1, 4);
                sa += __shfl_xor(sa, 2, 4);
                sb += __shfl_xor(sb, 1, 4);
                sb += __shfl_xor(sb, 2, 4);
                const float eA = __expf(sa * pri);
                const float eB = hB ? __expf(sb * pri) : 0.f;
                dd += eA + eB;
                #pragma unroll
                for (int x = 0; x < 8; x++) {
                    P[x]     = fmaf(eA, bf2f(vA0[x]), P[x]);
                    P[8 + x] = fmaf(eA, bf2f(vA1[x]), P[8 + x]);
                    P[x]     = fmaf(eB, bf2f(vB0[x]), P[x]);
                    P[8 + x] = fmaf(eB, bf2f(vB1[x]), P[8 + x]);
                }
                i += 2;
                if (i >= i1) break;
                sA = nA;
                sB = nB;
            }
        }
        u16x8 w0, w1;
        #pragma unroll
        for (int x = 0; x < 8; x++) {
            w0[x] = f2bf(P[x]);
            w1[x] = f2bf(P[8 + x]);
        }
        *((u16x8*)&pl[wave][sg][ll * 16])     = w0;
        *((u16x8*)&pl[wave][sg][ll * 16 + 8]) = w1;
        ddsum += dd;
        asm volatile("s_waitcnt lgkmcnt(0)" ::: "memory");

        // ---- U += P @ M_r ----
        const unsigned short* Mr = Mt + ((size_t)r << 12);
        const bf16x8 pa0 = *((const bf16x8*)&pl[wave][m][quad * 8]);
        const bf16x8 pa1 = *((const bf16x8*)&pl[wave][m][32 + quad * 8]);
        u0 = __builtin_amdgcn_mfma_f32_16x16x32_bf16(pa0, ldb16(Mr + (( 0 + m) << 6)      + quad * 8), u0, 0, 0, 0);
        u1 = __builtin_amdgcn_mfma_f32_16x16x32_bf16(pa0, ldb16(Mr + ((16 + m) << 6)      + quad * 8), u1, 0, 0, 0);
        u2 = __builtin_amdgcn_mfma_f32_16x16x32_bf16(pa0, ldb16(Mr + ((32 + m) << 6)      + quad * 8), u2, 0, 0, 0);
        u3 = __builtin_amdgcn_mfma_f32_16x16x32_bf16(pa0, ldb16(Mr + ((48 + m) << 6)      + quad * 8), u3, 0, 0, 0);
        u0 = __builtin_amdgcn_mfma_f32_16x16x32_bf16(pa1, ldb16(Mr + (( 0 + m) << 6) + 32 + quad * 8), u0, 0, 0, 0);
        u1 = __builtin_amdgcn_mfma_f32_16x16x32_bf16(pa1, ldb16(Mr + ((16 + m) << 6) + 32 + quad * 8), u1, 0, 0, 0);
        u2 = __builtin_amdgcn_mfma_f32_16x16x32_bf16(pa1, ldb16(Mr + ((32 + m) << 6) + 32 + quad * 8), u2, 0, 0, 0);
        u3 = __builtin_amdgcn_mfma_f32_16x16x32_bf16(pa1, ldb16(Mr + ((48 + m) << 6) + 32 + quad * 8), u3, 0, 0, 0);
        asm volatile("s_waitcnt lgkmcnt(0)" ::: "memory");
    }

    // ---- all waves done with qwb/pl; alias as f32 U-tile [4][16][68] ----
    __syncthreads();
    float* Ut = (float*)&smem[0][0][0][0];
    #pragma unroll
    for (int reg = 0; reg < 4; reg++) {
        const int row = quad * 4 + reg;
        const float dv  = __shfl(ddsum, row << 2, 64);
        const float inv = (dv == 0.f) ? 0.f : 1.f / dv;
        float* rp = Ut + ((size_t)(wave * 16 + row)) * 68 + m;
        rp[ 0] = u0[reg] * inv;
        rp[16] = u1[reg] * inv;
        rp[32] = u2[reg] * inv;
        rp[48] = u3[reg] * inv;
    }
    asm volatile("s_waitcnt lgkmcnt(0)" ::: "memory");   // same-wave rows only

    // ---- fused output GEMM: out[nid] = (U/D) @ W2, f32 ----
    const int og  = lane & 15;
    const int ng4 = (lane >> 4) * 4;
    float4 a0 = make_float4(0.f,0.f,0.f,0.f), a1 = a0, a2 = a0, a3 = a0;
    const float* xb = Ut + ((size_t)(wave * 16 + ng4)) * 68;
    #pragma unroll 8
    for (int d = 0; d < DIM; d++) {
        float4 wv = *((const float4*)&W2[d][og * 4]);
        float x0 = xb[d];
        float x1 = xb[68 + d];
        float x2 = xb[136 + d];
        float x3 = xb[204 + d];
        a0.x = fmaf(x0, wv.x, a0.x); a0.y = fmaf(x0, wv.y, a0.y);
        a0.z = fmaf(x0, wv.z, a0.z); a0.w = fmaf(x0, wv.w, a0.w);
        a1.x = fmaf(x1, wv.x, a1.x); a1.y = fmaf(x1, wv.y, a1.y);
        a1.z = fmaf(x1, wv.z, a1.z); a1.w = fmaf(x1, wv.w, a1.w);
        a2.x = fmaf(x2, wv.x, a2.x); a2.y = fmaf(x2, wv.y, a2.y);
        a2.z = fmaf(x2, wv.z, a2.z); a2.w = fmaf(x2, wv.w, a2.w);
        a3.x = fmaf(x3, wv.x, a3.x); a3.y = fmaf(x3, wv.y, a3.y);
        a3.z = fmaf(x3, wv.z, a3.z); a3.w = fmaf(x3, wv.w, a3.w);
    }
    const int g0 = order[n0 + ng4 + 0];
    const int g1 = order[n0 + ng4 + 1];
    const int g2 = order[n0 + ng4 + 2];
    const int g3 = order[n0 + ng4 + 3];
    if (g0 >= 0) ((float4*)(out + (size_t)g0 * DIM))[og] = a0;
    if (g1 >= 0) ((float4*)(out + (size_t)g1 * DIM))[og] = a1;
    if (g2 >= 0) ((float4*)(out + (size_t)g2 * DIM))[og] = a2;
    if (g3 >= 0) ((float4*)(out + (size_t)g3 * DIM))[og] = a3;
}

extern "C" void kernel_launch(void* const* d_in, const int* in_sizes, int n_in,
                              void* d_out, int out_size, void* d_ws, size_t ws_size,
                              hipStream_t stream) {
    const float* h       = (const float*)d_in[0];
    const int*   ntype   = (const int*)  d_in[1];
    const int*   src     = (const int*)  d_in[2];
    const int*   dst     = (const int*)  d_in[3];
    const int*   et      = (const int*)  d_in[4];
    const float* k_lin   = (const float*)d_in[5];
    const float* q_lin   = (const float*)d_in[6];
    const float* v_lin   = (const float*)d_in[7];
    const float* a_lin   = (const float*)d_in[8];
    const float* rel_att = (const float*)d_in[9];
    const float* rel_msg = (const float*)d_in[10];
    const float* rel_pri = (const float*)d_in[11];
    const float* skip    = (const float*)d_in[12];

    int N = in_sizes[1];
    int E = in_sizes[2];
    int gridT = (N + NT * 64 + 63) / 64;
    int ocap2 = gridT * 64;          // every position any block can touch
    int M2 = ocap2 * NR;             // position-keyed bucket space

    float* ws = (float*)d_ws;
    size_t o = 0;
    unsigned short* kvbf = (unsigned short*)(ws + o); o += (size_t)N * DIM;         // kv[n][128] bf16
    unsigned short* qbf  = (unsigned short*)(ws + o); o += (size_t)ocap2 * DIM / 2; // SORTED q
    int* off8   = (int*)(ws + o); o += (size_t)M2 + 1024;
    int* cnt8   = (int*)(ws + o); o += (size_t)M2;
    int* rank   = (int*)(ws + o); o += (size_t)E;
    int* se     = (int*)(ws + o); o += (size_t)E;
    int* bsum   = (int*)(ws + o); o += 1024;
    int* order  = (int*)(ws + o); o += (size_t)ocap2;
    int* pos    = (int*)(ws + o); o += (size_t)N;
    int* tm     = (int*)(ws + o); o += 16;
    unsigned short* At  = (unsigned short*)(ws + o); o += (size_t)NR * DIM * DIM / 2;
    unsigned short* Mt  = (unsigned short*)(ws + o); o += (size_t)NR * DIM * DIM / 2;
    unsigned short* Wkt = (unsigned short*)(ws + o); o += (size_t)NT * DIM * DIM / 2;
    unsigned short* Wqt = (unsigned short*)(ws + o); o += (size_t)NT * DIM * DIM / 2;
    unsigned short* Wvt = (unsigned short*)(ws + o); o += (size_t)NT * DIM * DIM / 2;

    float* out = (float*)d_out;

    // ---- prep: weight transpose/cast + zero cnt8/tm (one kernel) ----
    int gprep = (M2 > 28 * DIM * DIM ? M2 : 28 * DIM * DIM);
    prep_all<<<(gprep + 255) / 256, 256, 0, stream>>>(
        rel_att, rel_msg, k_lin, q_lin, v_lin, At, Mt, Wkt, Wqt, Wvt, cnt8, tm, M2);

    // ---- type sort (order init fused into type_count) ----
    type_count<<<(ocap2 + 255) / 256, 256, 0, stream>>>(ntype, tm, order, N, ocap2);
    type_scan<<<1, 64, 0, stream>>>(tm);
    type_scatter<<<(N + 255) / 256, 256, 0, stream>>>(ntype, tm, order, pos, N);

    // ---- typed K/Q/V projections via MFMA (sorted tiles) ----
    proj_mfma<<<gridT, 256, 0, stream>>>(h, ntype, order, tm, Wkt, Wqt, Wvt,
                                         kvbf, qbf, N);

    // ---- CSR build over sorted-position buckets ----
    hist8<<<(E + 255) / 256, 256, 0, stream>>>(dst, et, pos, cnt8, rank, E);
    int nb = (M2 + 1023) / 1024;
    scan1<<<nb, 1024, 0, stream>>>(cnt8, off8, bsum, M2);
    scan2<<<1, 1024, 0, stream>>>(bsum, nb);
    scan3<<<nb, 1024, 0, stream>>>(off8, bsum, M2, E);
    scatter8<<<(E + 255) / 256, 256, 0, stream>>>(src, dst, et, pos, off8, rank, se, E);

    // ---- fused edge phase + output GEMM (sorted tiles) ----
    fused_edge<<<gridT, 256, 0, stream>>>(qbf, kvbf, At, Mt, se, off8, rel_pri,
                                          ntype, order, tm, a_lin, skip, out, N);
}

// Round 18
// 558.813 us; speedup vs baseline: 1.0275x; 1.0275x over previous
//
#include <hip/hip_runtime.h>
#include <math.h>

#define DIM 64
#define NT 4
#define NR 8
// tm layout: [0..3]=tcnt  [8..11]=tfill  (bases/total computed inline)

typedef __attribute__((ext_vector_type(8))) short bf16x8;   // 8 bf16 (4 VGPRs)
typedef __attribute__((ext_vector_type(8))) unsigned short u16x8;
typedef __attribute__((ext_vector_type(4))) float f32x4;    // 4 fp32 acc

// ---- bf16 helpers (bit-level; values finite/small) ----
__device__ __forceinline__ unsigned short f2bf(float f) {
    unsigned u = __float_as_uint(f);
    return (unsigned short)((u + 0x7FFF + ((u >> 16) & 1)) >> 16);  // RNE
}
__device__ __forceinline__ float bf2f(unsigned short u) {
    return __uint_as_float((unsigned)u << 16);
}
__device__ __forceinline__ bf16x8 ldb16(const unsigned short* p) {
    return *((const bf16x8*)p);
}
__device__ __forceinline__ int padt(int x) { return (x + 63) & ~63; }

// ---- prep: weight transpose+cast, plus workspace zero-init (fused) ----
// mats: 0..7 = rel_att, 8..15 = rel_msg, 16..19 = k_lin, 20..23 = q_lin, 24..27 = v_lin
__global__ void prep_all(const float* __restrict__ A, const float* __restrict__ Mw,
                         const float* __restrict__ kl, const float* __restrict__ ql,
                         const float* __restrict__ vl,
                         unsigned short* __restrict__ At, unsigned short* __restrict__ Mt,
                         unsigned short* __restrict__ Wkt, unsigned short* __restrict__ Wqt,
                         unsigned short* __restrict__ Wvt,
                         int* __restrict__ cnt8, int* __restrict__ tm, int M2) {
    int i = blockIdx.x * blockDim.x + threadIdx.x;
    if (i < M2) cnt8[i] = 0;
    if (i < 16) tm[i] = 0;
    if (i >= 28 * DIM * DIM) return;
    int mat = i >> 12;
    int idx = i & 4095;
    int n = idx >> 6;
    int k = idx & 63;
    int so = k * DIM + n;
    if (mat < 8)       At [((size_t)mat << 12) + idx]        = f2bf(A [((size_t)mat << 12) + so]);
    else if (mat < 16) Mt [((size_t)(mat - 8) << 12) + idx]  = f2bf(Mw[((size_t)(mat - 8) << 12) + so]);
    else if (mat < 20) Wkt[((size_t)(mat - 16) << 12) + idx] = f2bf(kl[((size_t)(mat - 16) << 12) + so]);
    else if (mat < 24) Wqt[((size_t)(mat - 20) << 12) + idx] = f2bf(ql[((size_t)(mat - 20) << 12) + so]);
    else               Wvt[((size_t)(mat - 24) << 12) + idx] = f2bf(vl[((size_t)(mat - 24) << 12) + so]);
}

// ---- per-wave ballot histogram of node types (+ order=-1 init, fused) ----
__global__ void type_count(const int* __restrict__ ntype, int* __restrict__ tm,
                           int* __restrict__ order, int N, int ocap2) {
    int i = blockIdx.x * blockDim.x + threadIdx.x;
    if (i < ocap2) order[i] = -1;
    int t = (i < N) ? ntype[i] : -1;
    int lane = threadIdx.x & 63;
    #pragma unroll
    for (int tt = 0; tt < NT; tt++) {
        unsigned long long m = __ballot(t == tt);
        int c = __popcll(m);
        if (c && lane == (__ffsll((long long)m) - 1)) atomicAdd(&tm[tt], c);
    }
}

// ---- scatter to sorted order; also writes pos[] (inverse permutation).
// Type bases computed inline from tm[0..3] (type_scan launch eliminated). ----
__global__ void type_scatter(const int* __restrict__ ntype, int* __restrict__ tm,
                             int* __restrict__ order, int* __restrict__ pos, int N) {
    int b1 = padt(tm[0]);
    int b2 = b1 + padt(tm[1]);
    int b3 = b2 + padt(tm[2]);
    int bases[4] = { 0, b1, b2, b3 };
    int i = blockIdx.x * blockDim.x + threadIdx.x;
    int t = (i < N) ? ntype[i] : -1;
    int lane = threadIdx.x & 63;
    #pragma unroll
    for (int tt = 0; tt < NT; tt++) {
        unsigned long long m = __ballot(t == tt);
        int c = __popcll(m);
        if (!c) continue;
        int ldr = __ffsll((long long)m) - 1;
        int base = 0;
        if (lane == ldr) base = atomicAdd(&tm[8 + tt], c);
        base = __shfl(base, ldr, 64);
        if (t == tt) {
            int rank = __popcll(m & ((1ull << lane) - 1ull));
            int p = bases[tt] + base + rank;
            order[p] = i;
            pos[i] = p;
        }
    }
}

// ---- typed K/Q/V projection via MFMA: sorted 64-node tile, LDS-staged
// coalesced stores. q written in SORTED layout; kv natural. ----
__global__ void __launch_bounds__(256)
proj_mfma(const float* __restrict__ h, const int* __restrict__ ntype,
          const int* __restrict__ order, const int* __restrict__ tm,
          const unsigned short* __restrict__ Wkt, const unsigned short* __restrict__ Wqt,
          const unsigned short* __restrict__ Wvt,
          unsigned short* __restrict__ kvbf, unsigned short* __restrict__ qbf, int N) {
    __shared__ __align__(16) unsigned short xs[64][72];
    int t  = threadIdx.x;
    int n0 = blockIdx.x * 64;
    int tot = padt(tm[0]) + padt(tm[1]) + padt(tm[2]) + padt(tm[3]);
    if (n0 >= tot) return;
    int first = order[n0];
    if (first < 0) return;
    int ty = ntype[first];

    // row -> global node (for h gather and kv scatter)
    int grow[2];
    #pragma unroll
    for (int i = 0; i < 2; i++) grow[i] = order[n0 + (t + 256 * i) / 8];

    // stage h tile as bf16 (padding rows = exact zeros)
    #pragma unroll
    for (int i = 0; i < 4; i++) {
        int idx = t + 256 * i;
        int row = idx >> 4, c4 = idx & 15;
        int gn = order[n0 + row];
        float4 xv = make_float4(0.f, 0.f, 0.f, 0.f);
        if (gn >= 0) xv = ((const float4*)(h + (size_t)gn * DIM))[c4];
        ushort4 b = make_ushort4(f2bf(xv.x), f2bf(xv.y), f2bf(xv.z), f2bf(xv.w));
        *((ushort4*)&xs[row][c4 * 4]) = b;
    }
    __syncthreads();

    int wave = t >> 6, lane = t & 63;
    int m = lane & 15, quad = lane >> 4;
    bf16x8 xa0 = *((const bf16x8*)&xs[wave * 16 + m][quad * 8]);
    bf16x8 xa1 = *((const bf16x8*)&xs[wave * 16 + m][32 + quad * 8]);

    const unsigned short* Wt[3] = { Wkt + (size_t)ty * 4096,
                                    Wqt + (size_t)ty * 4096,
                                    Wvt + (size_t)ty * 4096 };
    for (int mm = 0; mm < 3; mm++) {
        const unsigned short* W = Wt[mm];
        f32x4 c0 = {0.f,0.f,0.f,0.f}, c1 = c0, c2 = c0, c3 = c0;
        c0 = __builtin_amdgcn_mfma_f32_16x16x32_bf16(xa0, ldb16(W + (( 0 + m) << 6)      + quad * 8), c0, 0, 0, 0);
        c1 = __builtin_amdgcn_mfma_f32_16x16x32_bf16(xa0, ldb16(W + ((16 + m) << 6)      + quad * 8), c1, 0, 0, 0);
        c2 = __builtin_amdgcn_mfma_f32_16x16x32_bf16(xa0, ldb16(W + ((32 + m) << 6)      + quad * 8), c2, 0, 0, 0);
        c3 = __builtin_amdgcn_mfma_f32_16x16x32_bf16(xa0, ldb16(W + ((48 + m) << 6)      + quad * 8), c3, 0, 0, 0);
        c0 = __builtin_amdgcn_mfma_f32_16x16x32_bf16(xa1, ldb16(W + (( 0 + m) << 6) + 32 + quad * 8), c0, 0, 0, 0);
        c1 = __builtin_amdgcn_mfma_f32_16x16x32_bf16(xa1, ldb16(W + ((16 + m) << 6) + 32 + quad * 8), c1, 0, 0, 0);
        c2 = __builtin_amdgcn_mfma_f32_16x16x32_bf16(xa1, ldb16(W + ((32 + m) << 6) + 32 + quad * 8), c2, 0, 0, 0);
        c3 = __builtin_amdgcn_mfma_f32_16x16x32_bf16(xa1, ldb16(W + ((48 + m) << 6) + 32 + quad * 8), c3, 0, 0, 0);

        // D (row=quad*4+reg, col=m+16*nb) -> LDS stage (xs reused)
        __syncthreads();
        #pragma unroll
        for (int reg = 0; reg < 4; reg++) {
            unsigned short* qr = &xs[wave * 16 + quad * 4 + reg][m];
            qr[ 0] = f2bf(c0[reg]); qr[16] = f2bf(c1[reg]);
            qr[32] = f2bf(c2[reg]); qr[48] = f2bf(c3[reg]);
        }
        __syncthreads();
        // coalesced 16B stores
        #pragma unroll
        for (int i = 0; i < 2; i++) {
            int idx = t + 256 * i;
            int row = idx >> 3, c8 = idx & 7;
            u16x8 v = *((const u16x8*)&xs[row][c8 * 8]);
            if (mm == 1) {
                *((u16x8*)(qbf + ((size_t)(n0 + row) << 6) + c8 * 8)) = v;
            } else {
                int gn = grow[i];
                if (gn >= 0) {
                    unsigned short* dp = (mm == 0)
                        ? kvbf + ((size_t)gn << 7) + c8 * 8
                        : kvbf + ((size_t)gn << 7) + 64 + c8 * 8;
                    *((u16x8*)dp) = v;
                }
            }
        }
    }
}

// ------- CSR build over (pos(dst)*8 + etype) buckets: SORTED-position keys.
// hist8 records each edge's within-bucket rank -> atomic-free scatter. -------
__global__ void hist8(const int* __restrict__ dst, const int* __restrict__ et,
                      const int* __restrict__ pos,
                      int* __restrict__ cnt, int* __restrict__ rank, int E) {
    int e = blockIdx.x * blockDim.x + threadIdx.x;
    if (e < E) rank[e] = atomicAdd(&cnt[pos[dst[e]] * NR + et[e]], 1);
}

// shuffle-based block scan: 3 barriers instead of 20
__global__ void scan1(const int* __restrict__ cnt, int* __restrict__ off,
                      int* __restrict__ bsum, int M) {
    __shared__ int wsum[16];
    int tid = threadIdx.x;
    int lane = tid & 63, wid = tid >> 6;
    int i = blockIdx.x * 1024 + tid;
    int x0 = (i < M) ? cnt[i] : 0;
    int x = x0;
    #pragma unroll
    for (int s = 1; s < 64; s <<= 1) {
        int y = __shfl_up(x, s, 64);
        if (lane >= s) x += y;
    }
    if (lane == 63) wsum[wid] = x;
    __syncthreads();
    if (tid < 16) {
        int w = wsum[tid];
        #pragma unroll
        for (int s = 1; s < 16; s <<= 1) {
            int y = __shfl_up(w, s, 16);
            if (tid >= s) w += y;
        }
        wsum[tid] = w;   // inclusive wave-sum scan
    }
    __syncthreads();
    int add = (wid > 0) ? wsum[wid - 1] : 0;
    if (i < M) off[i] = add + x - x0;            // exclusive
    if (tid == 1023) bsum[blockIdx.x] = wsum[15]; // block total
}

__global__ void scan2(int* __restrict__ bsum, int nb) {
    __shared__ int wsum[16];
    __shared__ int carry;
    int tid = threadIdx.x;
    int lane = tid & 63, wid = tid >> 6;
    if (tid == 0) carry = 0;
    __syncthreads();
    for (int base = 0; base < nb; base += 1024) {
        int i = base + tid;
        int x0 = (i < nb) ? bsum[i] : 0;
        int x = x0;
        #pragma unroll
        for (int s = 1; s < 64; s <<= 1) {
            int y = __shfl_up(x, s, 64);
            if (lane >= s) x += y;
        }
        if (lane == 63) wsum[wid] = x;
        __syncthreads();
        if (tid < 16) {
            int w = wsum[tid];
            #pragma unroll
            for (int s = 1; s < 16; s <<= 1) {
                int y = __shfl_up(w, s, 16);
                if (tid >= s) w += y;
            }
            wsum[tid] = w;
        }
        __syncthreads();
        int add = carry + ((wid > 0) ? wsum[wid - 1] : 0);
        if (i < nb) bsum[i] = add + x - x0;   // exclusive
        __syncthreads();
        if (tid == 0) carry += wsum[15];
        __syncthreads();
    }
}

__global__ void scan3(int* __restrict__ off, const int* __restrict__ bsum, int M, int E) {
    int i = blockIdx.x * 1024 + threadIdx.x;
    if (i < M) off[i] += bsum[blockIdx.x];
    if (i == 0) off[M] = E;
}

__global__ void scatter8(const int* __restrict__ src, const int* __restrict__ dst,
                         const int* __restrict__ et, const int* __restrict__ pos,
                         const int* __restrict__ off,
                         const int* __restrict__ rank, int* __restrict__ se, int E) {
    int e = blockIdx.x * blockDim.x + threadIdx.x;
    if (e >= E) return;
    int key = pos[dst[e]] * NR + et[e];
    se[off[key] + rank[e]] = src[e];
}

// =====================================================================
// Fused edge phase + output GEMM over SORTED tiles (one type per tile).
// CSR keyed by sorted POSITION -> bucket offsets load COALESCED (v12,
// proven). Carried one-round-lookahead FIRST PAIR (v14/v16, proven) +
// rolling in-loop se prefetch (v17, neutral-kept). Total position count
// computed inline from tm[0..3] (type_scan launch eliminated).
// Epilogue: W2 = sigmoid(skip)*a_lin in LDS; U/D via LDS-aliased f32
// tile; out rows scattered directly.
// =====================================================================
__global__ void __launch_bounds__(256)
fused_edge(const unsigned short* __restrict__ qbf,      // SORTED layout
           const unsigned short* __restrict__ kvbf,     // natural layout
           const unsigned short* __restrict__ At,
           const unsigned short* __restrict__ Mt,
           const int* __restrict__ se, const int* __restrict__ off8,
           const float* __restrict__ rel_pri,
           const int* __restrict__ ntype, const int* __restrict__ order,
           const int* __restrict__ tm,
           const float* __restrict__ Wa, const float* __restrict__ skip,
           float* __restrict__ out, int N) {
    __shared__ __align__(16) unsigned short smem[2][4][16][72]; // qwb | pl (18432B)
    __shared__ __align__(16) float W2[64][64];                  // 16KB
    unsigned short (*qwb)[16][72] = smem[0];
    unsigned short (*pl)[16][72]  = smem[1];
    const int t    = threadIdx.x;
    const int wave = t >> 6;
    const int lane = t & 63;
    const int m    = lane & 15;      // MFMA col
    const int quad = lane >> 4;      // MFMA quad
    const int sg   = lane >> 2;      // walk: node owner (0..15)
    const int ll   = lane & 3;       // walk: dim-16 owner
    const int n0   = blockIdx.x * 64 + wave * 16;   // sorted position base
    const int tot  = padt(tm[0]) + padt(tm[1]) + padt(tm[2]) + padt(tm[3]);
    const bool blkvalid = (blockIdx.x * 64) < tot;

    // ---- stage W2 = sigmoid(skip[ty]) * Wa[ty] (block-uniform type) ----
    if (blkvalid) {
        const int ty = ntype[order[blockIdx.x * 64]];
        const float sgs = 1.f / (1.f + expf(-skip[ty]));
        const float4* wg = (const float4*)(Wa + (size_t)ty * DIM * DIM);
        float4* wl = (float4*)&W2[0][0];
        #pragma unroll
        for (int i = 0; i < 4; i++) {
            float4 w = wg[t + 256 * i];
            w.x *= sgs; w.y *= sgs; w.z *= sgs; w.w *= sgs;
            wl[t + 256 * i] = w;
        }
    }
    __syncthreads();
    if (!blkvalid) return;

    // ---- coalesced bucket offsets: 129 values for the wave's 16 positions ----
    const int ob  = n0 * NR;
    const int ov0 = off8[ob + lane];
    const int ov1 = off8[ob + 64 + lane];
    const int ov2 = off8[ob + 128];      // wave-uniform; defined up to off8[M2]=E

    // ---- round-0 bounds + first-pair prefetch ----
    int i0c, i1c, sAc, sBc;
    {
        const int g = sg * NR, g1 = g + 1;
        const int a0_ = __shfl(ov0, g & 63, 64);
        const int b0_ = __shfl(ov1, g & 63, 64);
        i0c = (g < 64) ? a0_ : b0_;
        const int a1_ = __shfl(ov0, g1 & 63, 64);
        const int b1_ = __shfl(ov1, g1 & 63, 64);
        i1c = (g1 < 64) ? a1_ : ((g1 < 128) ? b1_ : ov2);
        sAc = (i0c < i1c)     ? se[i0c]     : 0;
        sBc = (i0c + 1 < i1c) ? se[i0c + 1] : sAc;
    }

    // Q A-frags from sorted qbf (padding rows are zeros)
    const unsigned short* qp = qbf + ((size_t)(n0 + m) << 6) + quad * 8;
    const bf16x8 qa0 = *((const bf16x8*)qp);
    const bf16x8 qa1 = *((const bf16x8*)(qp + 32));

    f32x4 u0 = {0.f,0.f,0.f,0.f}, u1 = u0, u2 = u0, u3 = u0;  // U accumulator
    float ddsum = 0.f;   // node sg's denominator (replicated over 4 lanes)

    for (int r = 0; r < NR; r++) {
        // ---- qW tile via MFMA ----
        const unsigned short* Ar = At + ((size_t)r << 12);
        f32x4 c0 = {0.f,0.f,0.f,0.f}, c1 = c0, c2 = c0, c3 = c0;
        c0 = __builtin_amdgcn_mfma_f32_16x16x32_bf16(qa0, ldb16(Ar + (( 0 + m) << 6)      + quad * 8), c0, 0, 0, 0);
        c1 = __builtin_amdgcn_mfma_f32_16x16x32_bf16(qa0, ldb16(Ar + ((16 + m) << 6)      + quad * 8), c1, 0, 0, 0);
        c2 = __builtin_amdgcn_mfma_f32_16x16x32_bf16(qa0, ldb16(Ar + ((32 + m) << 6)      + quad * 8), c2, 0, 0, 0);
        c3 = __builtin_amdgcn_mfma_f32_16x16x32_bf16(qa0, ldb16(Ar + ((48 + m) << 6)      + quad * 8), c3, 0, 0, 0);
        c0 = __builtin_amdgcn_mfma_f32_16x16x32_bf16(qa1, ldb16(Ar + (( 0 + m) << 6) + 32 + quad * 8), c0, 0, 0, 0);
        c1 = __builtin_amdgcn_mfma_f32_16x16x32_bf16(qa1, ldb16(Ar + ((16 + m) << 6) + 32 + quad * 8), c1, 0, 0, 0);
        c2 = __builtin_amdgcn_mfma_f32_16x16x32_bf16(qa1, ldb16(Ar + ((32 + m) << 6) + 32 + quad * 8), c2, 0, 0, 0);
        c3 = __builtin_amdgcn_mfma_f32_16x16x32_bf16(qa1, ldb16(Ar + ((48 + m) << 6) + 32 + quad * 8), c3, 0, 0, 0);

        #pragma unroll
        for (int reg = 0; reg < 4; reg++) {
            unsigned short* qr = &qwb[wave][quad * 4 + reg][m];
            qr[ 0] = f2bf(c0[reg]); qr[16] = f2bf(c1[reg]);
            qr[32] = f2bf(c2[reg]); qr[48] = f2bf(c3[reg]);
        }
        asm volatile("s_waitcnt lgkmcnt(0)" ::: "memory");

        // ---- current-round bounds/first-pair from carried registers ----
        const int i0  = i0c;
        const int i1  = i1c;
        const int sA1 = sAc;
        const int sB1 = sBc;
        // ---- prefetch NEXT round's bounds + first pair (hidden under walk+MFMA) ----
        if (r < 7) {
            const int g = sg * NR + r + 1, g1 = g + 1;
            const int a0_ = __shfl(ov0, g & 63, 64);
            const int b0_ = __shfl(ov1, g & 63, 64);
            i0c = (g < 64) ? a0_ : b0_;
            const int a1_ = __shfl(ov0, g1 & 63, 64);
            const int b1_ = __shfl(ov1, g1 & 63, 64);
            i1c = (g1 < 64) ? a1_ : ((g1 < 128) ? b1_ : ov2);
            sAc = (i0c < i1c)     ? se[i0c]     : 0;
            sBc = (i0c + 1 < i1c) ? se[i0c + 1] : sAc;
        }

        const float pri = rel_pri[r] * 0.125f;
        float P[16];
        #pragma unroll
        for (int x = 0; x < 16; x++) P[x] = 0.f;
        float dd = 0.f;

        if (i0 < i1) {
            const u16x8 tq0 = *((const u16x8*)&qwb[wave][sg][ll * 16]);
            const u16x8 tq1 = *((const u16x8*)&qwb[wave][sg][ll * 16 + 8]);
            float tq[16];
            #pragma unroll
            for (int x = 0; x < 8; x++) { tq[x] = bf2f(tq0[x]); tq[8 + x] = bf2f(tq1[x]); }

            int i  = i0;
            int sA = sA1;
            int sB = sB1;
            while (true) {
                const bool hB = (i + 1 < i1);
                // rolling prefetch of the NEXT pair's se (completes under the
                // current pair's kv gather + dot/exp)
                int nA = 0, nB = 0;
                if (i + 2 < i1) {
                    nA = se[i + 2];
                    nB = (i + 3 < i1) ? se[i + 3] : nA;
                }
                const unsigned short* pA = kvbf + ((size_t)sA << 7) + ll * 16;
                const unsigned short* pB = kvbf + ((size_t)sB << 7) + ll * 16;
                const u16x8 kA0 = *((const u16x8*)pA);
                const u16x8 kA1 = *((const u16x8*)(pA + 8));
                const u16x8 vA0 = *((const u16x8*)(pA + 64));
                const u16x8 vA1 = *((const u16x8*)(pA + 72));
                const u16x8 kB0 = *((const u16x8*)pB);
                const u16x8 kB1 = *((const u16x8*)(pB + 8));
                const u16x8 vB0 = *((const u16x8*)(pB + 64));
                const u16x8 vB1 = *((const u16x8*)(pB + 72));
                float sa = 0.f, sb = 0.f;
                #pragma unroll
                for (int x = 0; x < 8; x++) {
                    sa = fmaf(bf2f(kA0[x]), tq[x],     sa);
                    sa = fmaf(bf2f(kA1[x]), tq[8 + x], sa);
                    sb = fmaf(bf2f(kB0[x]), tq[x],     sb);
                    sb = fmaf(bf2f(kB1[x]), tq[8 + x], sb);
                }
                sa += __shfl_xor(sa, 1, 4);
                sa += __shfl_xor(sa, 2, 4);
                sb += __shfl_xor(sb, 1, 4);
                sb += __shfl_xor(sb, 2, 4);
                const float eA = __expf(sa * pri);
                const float eB = hB ? __expf(sb * pri) : 0.f;
                dd += eA + eB;
                #pragma unroll
                for (int x = 0; x < 8; x++) {
                    P[x]     = fmaf(eA, bf2f(vA0[x]), P[x]);
                    P[8 + x] = fmaf(eA, bf2f(vA1[x]), P[8 + x]);
                    P[x]     = fmaf(eB, bf2f(vB0[x]), P[x]);
                    P[8 + x] = fmaf(eB, bf2f(vB1[x]), P[8 + x]);
                }
                i += 2;
                if (i >= i1) break;
                sA = nA;
                sB = nB;
            }
        }
        u16x8 w0, w1;
        #pragma unroll
        for (int x = 0; x < 8; x++) {
            w0[x] = f2bf(P[x]);
            w1[x] = f2bf(P[8 + x]);
        }
        *((u16x8*)&pl[wave][sg][ll * 16])     = w0;
        *((u16x8*)&pl[wave][sg][ll * 16 + 8]) = w1;
        ddsum += dd;
        asm volatile("s_waitcnt lgkmcnt(0)" ::: "memory");

        // ---- U += P @ M_r ----
        const unsigned short* Mr = Mt + ((size_t)r << 12);
        const bf16x8 pa0 = *((const bf16x8*)&pl[wave][m][quad * 8]);
        const bf16x8 pa1 = *((const bf16x8*)&pl[wave][m][32 + quad * 8]);
        u0 = __builtin_amdgcn_mfma_f32_16x16x32_bf16(pa0, ldb16(Mr + (( 0 + m) << 6)      + quad * 8), u0, 0, 0, 0);
        u1 = __builtin_amdgcn_mfma_f32_16x16x32_bf16(pa0, ldb16(Mr + ((16 + m) << 6)      + quad * 8), u1, 0, 0, 0);
        u2 = __builtin_amdgcn_mfma_f32_16x16x32_bf16(pa0, ldb16(Mr + ((32 + m) << 6)      + quad * 8), u2, 0, 0, 0);
        u3 = __builtin_amdgcn_mfma_f32_16x16x32_bf16(pa0, ldb16(Mr + ((48 + m) << 6)      + quad * 8), u3, 0, 0, 0);
        u0 = __builtin_amdgcn_mfma_f32_16x16x32_bf16(pa1, ldb16(Mr + (( 0 + m) << 6) + 32 + quad * 8), u0, 0, 0, 0);
        u1 = __builtin_amdgcn_mfma_f32_16x16x32_bf16(pa1, ldb16(Mr + ((16 + m) << 6) + 32 + quad * 8), u1, 0, 0, 0);
        u2 = __builtin_amdgcn_mfma_f32_16x16x32_bf16(pa1, ldb16(Mr + ((32 + m) << 6) + 32 + quad * 8), u2, 0, 0, 0);
        u3 = __builtin_amdgcn_mfma_f32_16x16x32_bf16(pa1, ldb16(Mr + ((48 + m) << 6) + 32 + quad * 8), u3, 0, 0, 0);
        asm volatile("s_waitcnt lgkmcnt(0)" ::: "memory");
    }

    // ---- all waves done with qwb/pl; alias as f32 U-tile [4][16][68] ----
    __syncthreads();
    float* Ut = (float*)&smem[0][0][0][0];
    #pragma unroll
    for (int reg = 0; reg < 4; reg++) {
        const int row = quad * 4 + reg;
        const float dv  = __shfl(ddsum, row << 2, 64);
        const float inv = (dv == 0.f) ? 0.f : 1.f / dv;
        float* rp = Ut + ((size_t)(wave * 16 + row)) * 68 + m;
        rp[ 0] = u0[reg] * inv;
        rp[16] = u1[reg] * inv;
        rp[32] = u2[reg] * inv;
        rp[48] = u3[reg] * inv;
    }
    asm volatile("s_waitcnt lgkmcnt(0)" ::: "memory");   // same-wave rows only

    // ---- fused output GEMM: out[nid] = (U/D) @ W2, f32 ----
    const int og  = lane & 15;
    const int ng4 = (lane >> 4) * 4;
    float4 a0 = make_float4(0.f,0.f,0.f,0.f), a1 = a0, a2 = a0, a3 = a0;
    const float* xb = Ut + ((size_t)(wave * 16 + ng4)) * 68;
    #pragma unroll 8
    for (int d = 0; d < DIM; d++) {
        float4 wv = *((const float4*)&W2[d][og * 4]);
        float x0 = xb[d];
        float x1 = xb[68 + d];
        float x2 = xb[136 + d];
        float x3 = xb[204 + d];
        a0.x = fmaf(x0, wv.x, a0.x); a0.y = fmaf(x0, wv.y, a0.y);
        a0.z = fmaf(x0, wv.z, a0.z); a0.w = fmaf(x0, wv.w, a0.w);
        a1.x = fmaf(x1, wv.x, a1.x); a1.y = fmaf(x1, wv.y, a1.y);
        a1.z = fmaf(x1, wv.z, a1.z); a1.w = fmaf(x1, wv.w, a1.w);
        a2.x = fmaf(x2, wv.x, a2.x); a2.y = fmaf(x2, wv.y, a2.y);
        a2.z = fmaf(x2, wv.z, a2.z); a2.w = fmaf(x2, wv.w, a2.w);
        a3.x = fmaf(x3, wv.x, a3.x); a3.y = fmaf(x3, wv.y, a3.y);
        a3.z = fmaf(x3, wv.z, a3.z); a3.w = fmaf(x3, wv.w, a3.w);
    }
    const int g0 = order[n0 + ng4 + 0];
    const int g1 = order[n0 + ng4 + 1];
    const int g2 = order[n0 + ng4 + 2];
    const int g3 = order[n0 + ng4 + 3];
    if (g0 >= 0) ((float4*)(out + (size_t)g0 * DIM))[og] = a0;
    if (g1 >= 0) ((float4*)(out + (size_t)g1 * DIM))[og] = a1;
    if (g2 >= 0) ((float4*)(out + (size_t)g2 * DIM))[og] = a2;
    if (g3 >= 0) ((float4*)(out + (size_t)g3 * DIM))[og] = a3;
}

extern "C" void kernel_launch(void* const* d_in, const int* in_sizes, int n_in,
                              void* d_out, int out_size, void* d_ws, size_t ws_size,
                              hipStream_t stream) {
    const float* h       = (const float*)d_in[0];
    const int*   ntype   = (const int*)  d_in[1];
    const int*   src     = (const int*)  d_in[2];
    const int*   dst     = (const int*)  d_in[3];
    const int*   et      = (const int*)  d_in[4];
    const float* k_lin   = (const float*)d_in[5];
    const float* q_lin   = (const float*)d_in[6];
    const float* v_lin   = (const float*)d_in[7];
    const float* a_lin   = (const float*)d_in[8];
    const float* rel_att = (const float*)d_in[9];
    const float* rel_msg = (const float*)d_in[10];
    const float* rel_pri = (const float*)d_in[11];
    const float* skip    = (const float*)d_in[12];

    int N = in_sizes[1];
    int E = in_sizes[2];
    int gridT = (N + NT * 64 + 63) / 64;
    int ocap2 = gridT * 64;          // every position any block can touch
    int M2 = ocap2 * NR;             // position-keyed bucket space

    float* ws = (float*)d_ws;
    size_t o = 0;
    unsigned short* kvbf = (unsigned short*)(ws + o); o += (size_t)N * DIM;         // kv[n][128] bf16
    unsigned short* qbf  = (unsigned short*)(ws + o); o += (size_t)ocap2 * DIM / 2; // SORTED q
    int* off8   = (int*)(ws + o); o += (size_t)M2 + 1024;
    int* cnt8   = (int*)(ws + o); o += (size_t)M2;
    int* rank   = (int*)(ws + o); o += (size_t)E;
    int* se     = (int*)(ws + o); o += (size_t)E;
    int* bsum   = (int*)(ws + o); o += 1024;
    int* order  = (int*)(ws + o); o += (size_t)ocap2;
    int* pos    = (int*)(ws + o); o += (size_t)N;
    int* tm     = (int*)(ws + o); o += 16;
    unsigned short* At  = (unsigned short*)(ws + o); o += (size_t)NR * DIM * DIM / 2;
    unsigned short* Mt  = (unsigned short*)(ws + o); o += (size_t)NR * DIM * DIM / 2;
    unsigned short* Wkt = (unsigned short*)(ws + o); o += (size_t)NT * DIM * DIM / 2;
    unsigned short* Wqt = (unsigned short*)(ws + o); o += (size_t)NT * DIM * DIM / 2;
    unsigned short* Wvt = (unsigned short*)(ws + o); o += (size_t)NT * DIM * DIM / 2;

    float* out = (float*)d_out;

    // ---- prep: weight transpose/cast + zero cnt8/tm (one kernel) ----
    int gprep = (M2 > 28 * DIM * DIM ? M2 : 28 * DIM * DIM);
    prep_all<<<(gprep + 255) / 256, 256, 0, stream>>>(
        rel_att, rel_msg, k_lin, q_lin, v_lin, At, Mt, Wkt, Wqt, Wvt, cnt8, tm, M2);

    // ---- type sort (order init fused into type_count; no type_scan launch) ----
    type_count<<<(ocap2 + 255) / 256, 256, 0, stream>>>(ntype, tm, order, N, ocap2);
    type_scatter<<<(N + 255) / 256, 256, 0, stream>>>(ntype, tm, order, pos, N);

    // ---- typed K/Q/V projections via MFMA (sorted tiles) ----
    proj_mfma<<<gridT, 256, 0, stream>>>(h, ntype, order, tm, Wkt, Wqt, Wvt,
                                         kvbf, qbf, N);

    // ---- CSR build over sorted-position buckets ----
    hist8<<<(E + 255) / 256, 256, 0, stream>>>(dst, et, pos, cnt8, rank, E);
    int nb = (M2 + 1023) / 1024;
    scan1<<<nb, 1024, 0, stream>>>(cnt8, off8, bsum, M2);
    scan2<<<1, 1024, 0, stream>>>(bsum, nb);
    scan3<<<nb, 1024, 0, stream>>>(off8, bsum, M2, E);
    scatter8<<<(E + 255) / 256, 256, 0, stream>>>(src, dst, et, pos, off8, rank, se, E);

    // ---- fused edge phase + output GEMM (sorted tiles) ----
    fused_edge<<<gridT, 256, 0, stream>>>(qbf, kvbf, At, Mt, se, off8, rel_pri,
                                          ntype, order, tm, a_lin, skip, out, N);
}